// Round 8
// baseline (2919.508 us; speedup 1.0000x reference)
//
#include <hip/hip_runtime.h>
#include <hip/hip_bf16.h>

// HMM backward recursion, B=32, T=256, H=1024, V=50257.
// y_s[b,i] = N_{s-1}[b] + log( sum_j expA[i,j] * Y_{s-1}[b,j] ) + e_t[b,i]
// Y_s = exp(y_s - N_s), N_s = max_i y_{s-1}[b,i] (one-step-stale upper bound).
//
// Fire-and-forget exchange (sc0sc1, device scope): NO drains, NO flags.
//  - Y values are sign-parity tagged: step s stores (-1)^((s>>1)&1) * Y.
//    Each parity buffer alternates sign every reuse; consumer checks the
//    sign bit of every bf16 and retries until all fresh. 2B stores atomic.
//  - max records are [f32 max, u32 tag=s+1] 8B pairs (64-bit atomic).
//  - WAR safety: consumer proceeds only when ALL 64 producer waves' records
//    are fresh; a wave's stores are issued only after its loads drained.

#define Hdim 1024
#define Bdim 32
#define Tdim 256
#define Vdim 50257
#define NWG  16
#define SLICE 64

typedef __attribute__((ext_vector_type(8))) __bf16 bf16x8;
typedef __attribute__((ext_vector_type(4))) float  f32x4;
typedef __attribute__((ext_vector_type(4))) unsigned u32x4;
typedef __attribute__((ext_vector_type(2))) unsigned u32x2;

// workspace layout (bytes)
#define OFF_ABF   0                          // exp(alpha) bf16: 2 MB
#define OFF_YBUF  2097152                    // [2][16][4096B] = 131072
#define OFF_PSUM  (OFF_YBUF + 131072)        // 32 f32 (pad 128)
#define OFF_RBUF  (OFF_PSUM + 128)           // 32 f32 (pad 128)
#define OFF_WREC  (OFF_RBUF + 128)           // [2][16][4][4][4] x 8B = 16384
#define OFF_END0  (OFF_WREC + 16384)
#define OFF_E     (((OFF_END0) + 4095) & ~4095)
#define WS_E_NEED ((size_t)OFF_E + (size_t)Tdim * Bdim * Hdim * 4)

// LDS carve
#define SM_A       131072                    // 64 rows x 1024 bf16 (swizzled)
#define SMEM_BYTES (SM_A + 256)

// ---- sc0 sc1 (device-scope, cache-bypass) access helpers ----
__device__ __forceinline__ void st_b16_sc(void* p, unsigned v) {
    asm volatile("global_store_short %0, %1, off sc0 sc1" :: "v"(p), "v"(v) : "memory");
}
__device__ __forceinline__ void st_b64_sc(void* p, u32x2 v) {
    asm volatile("global_store_dwordx2 %0, %1, off sc0 sc1" :: "v"(p), "v"(v) : "memory");
}
__device__ __forceinline__ u32x4 ld_b128_sc(const void* p) {
    u32x4 r;
    asm volatile("global_load_dwordx4 %0, %1, off sc0 sc1" : "=v"(r) : "v"(p) : "memory");
    return r;
}
__device__ __forceinline__ u32x2 ld_b64_sc(const void* p) {
    u32x2 r;
    asm volatile("global_load_dwordx2 %0, %1, off sc0 sc1" : "=v"(r) : "v"(p) : "memory");
    return r;
}
__device__ __forceinline__ void waitcnt_vm0() {
    asm volatile("s_waitcnt vmcnt(0)" ::: "memory");
    __builtin_amdgcn_sched_barrier(0);
}

__global__ void k_expA(const float* __restrict__ alpha, __bf16* __restrict__ Abf) {
    int idx = (blockIdx.x * 256 + threadIdx.x) * 4;
    float4 v = *(const float4*)(alpha + idx);
    union { __bf16 h[4]; uint2 u; } cv;
    cv.h[0] = (__bf16)__expf(v.x);
    cv.h[1] = (__bf16)__expf(v.y);
    cv.h[2] = (__bf16)__expf(v.z);
    cv.h[3] = (__bf16)__expf(v.w);
    *(uint2*)(Abf + idx) = cv.u;
}

// E[t][b][i] = beta[i, x[b,t]]
__global__ void k_gather(const int* __restrict__ x, const float* __restrict__ beta,
                         float* __restrict__ E) {
    int tb = blockIdx.x;            // t*32 + b
    int t  = tb >> 5, b = tb & 31;
    int xv = x[b * Tdim + t];
    int i  = threadIdx.x * 4;
    float4 v;
    v.x = beta[(size_t)(i + 0) * Vdim + xv];
    v.y = beta[(size_t)(i + 1) * Vdim + xv];
    v.z = beta[(size_t)(i + 2) * Vdim + xv];
    v.w = beta[(size_t)(i + 3) * Vdim + xv];
    *(float4*)(E + ((size_t)t * Bdim + b) * Hdim + i) = v;
}

__device__ __forceinline__ void load_e(const float* __restrict__ E,
                                       const float* __restrict__ beta,
                                       const int* __restrict__ x,
                                       int t, int b0, int i0, int useE, float e[2][4]) {
    if (useE) {
        #pragma unroll
        for (int u = 0; u < 2; ++u)
            #pragma unroll
            for (int r = 0; r < 4; ++r)
                e[u][r] = E[((size_t)t * Bdim + (b0 + r)) * Hdim + i0 + u * 16];
    } else {
        int xv[4];
        #pragma unroll
        for (int r = 0; r < 4; ++r) xv[r] = x[(b0 + r) * Tdim + t];
        #pragma unroll
        for (int u = 0; u < 2; ++u)
            #pragma unroll
            for (int r = 0; r < 4; ++r)
                e[u][r] = beta[(size_t)(i0 + u * 16) * Vdim + xv[r]];
    }
}

// Fire-and-forget publish: Y (sign-parity wneg applied) + [max,tag] records.
// No drains, no flags.
__device__ __forceinline__ void publish_wave(const float y[2][4], const float Gc[4],
                                             char* Yblk,     // Ybuf[par] + p*4096
                                             char* wrec_w,   // wrec[par][p][w]
                                             int li, int g, int np, int b0,
                                             unsigned tag, float wneg) {
    float mx[4];
    #pragma unroll
    for (int r = 0; r < 4; ++r) {
        #pragma unroll
        for (int u = 0; u < 2; ++u) {
            float Yn = __expf(y[u][r] - Gc[r]);
            __bf16 h = (__bf16)(Yn * wneg);
            unsigned hv = (unsigned)__builtin_bit_cast(unsigned short, h);
            st_b16_sc(Yblk + (b0 + r) * 128 + (np * 32 + u * 16 + li) * 2, hv);
        }
        float m = fmaxf(y[0][r], y[1][r]);
        m = fmaxf(m, __shfl_xor(m, 1, 16));
        m = fmaxf(m, __shfl_xor(m, 2, 16));
        m = fmaxf(m, __shfl_xor(m, 4, 16));
        m = fmaxf(m, __shfl_xor(m, 8, 16));
        mx[r] = m;
    }
    if (li == 0) {
        #pragma unroll
        for (int r = 0; r < 4; ++r) {
            u32x2 pr = { __builtin_bit_cast(unsigned, mx[r]), tag };
            st_b64_sc(wrec_w + g * 32 + r * 8, pr);
        }
    }
}

__launch_bounds__(256, 1)
__global__ void k_hmm(const int* __restrict__ x,
                      const float* __restrict__ beta,
                      const float* __restrict__ gamma,
                      const __bf16* __restrict__ Abf,
                      char* __restrict__ Yb,        // [2][16][4096B]
                      char* __restrict__ wrec,      // [2][16][4][4][4] x 8B
                      float* __restrict__ Psum,
                      float* __restrict__ Rbuf,
                      const float* __restrict__ Ebuf,
                      int useE)
{
    extern __shared__ char smem[];
    char* Asl = smem;

    const int p   = blockIdx.x;
    const int tid = threadIdx.x;
    const int w   = tid >> 6;
    const int l   = tid & 63;
    const int g   = l >> 4;
    const int li  = l & 15;
    const int mb  = w & 1;
    const int np  = w >> 1;
    const int b0  = mb * 16 + g * 4;
    const int i0  = p * SLICE + np * 32 + li;

    // wrec poll mapping: lane l checks wave wl_w of every WG for b-row wl_bi
    const int wl_bmb = (l >> 4) & 1;
    const int wl_w   = wl_bmb + ((l >> 5) << 1);
    const int wl_bi  = l & 15;
    const int wl_off = wl_w * 128 + (wl_bi >> 2) * 32 + (wl_bi & 3) * 8;

    // ---- stage A slice into LDS, XOR-swizzled for b128 reads ----
    #pragma unroll
    for (int rep = 0; rep < 32; ++rep) {
        int flat = rep * 256 + tid;
        int row  = flat >> 7;
        int c16  = flat & 127;
        uint4 v = *(const uint4*)((const char*)Abf + (size_t)(p * 64 + row) * 2048 + c16 * 16);
        int off = (row * 2048 + c16 * 16) ^ ((row & 7) << 4);
        *(uint4*)(Asl + off) = v;
    }
    __syncthreads();    // only barrier (A staging)

    // ---- init: y0 = e[:, T-1]; publish step 0 (positive parity, tag 1) ----
    {
        float y0[2][4];
        load_e(Ebuf, beta, x, Tdim - 1, b0, i0, useE, y0);
        float Gc0[4] = {0.f, 0.f, 0.f, 0.f};
        publish_wave(y0, Gc0, Yb + p * 4096,
                     wrec + (size_t)p * 512 + w * 128,
                     li, g, np, b0, 1u, 1.f);
    }

    float Nprev[4] = {0.f, 0.f, 0.f, 0.f};
    float ereg[2][4];
    load_e(Ebuf, beta, x, Tdim - 2, b0, i0, useE, ereg);

    for (int s = 1; s < Tdim; ++s) {
        const int t     = Tdim - 1 - s;
        const int par_r = (s - 1) & 1;
        const int par_w = s & 1;
        const unsigned want = (unsigned)s;                       // wrec tag
        const unsigned sgnr = (((s - 1) >> 1) & 1) ? 0x80008000u : 0u;
        const float    negr = (((s - 1) >> 1) & 1) ? -1.f : 1.f;
        const float    negw = ((s >> 1) & 1) ? -1.f : 1.f;

        // prefetch next step's e (plain cached loads; drained by poll's vmcnt)
        float eregN[2][4];
        if (s < Tdim - 1) load_e(Ebuf, beta, x, t - 1, b0, i0, useE, eregN);
        float gl[2] = {0.f, 0.f};
        if (s == Tdim - 1) { gl[0] = gamma[i0]; gl[1] = gamma[i0 + 16]; }

        // ---- self-validating consume: retry loads until all fresh ----
        const char* Ybase = Yb + (size_t)par_r * (NWG * 4096);
        const char* yrow  = Ybase + (mb * 16 + li) * 128 + g * 16;
        const char* wbase = wrec + (size_t)par_r * 8192 + wl_off;

        u32x4 yreg[32];
        u32x2 wr[16];
        int okc;
        do {
            #pragma unroll
            for (int kc = 0; kc < 32; ++kc)
                yreg[kc] = ld_b128_sc(yrow + (kc >> 1) * 4096 + (kc & 1) * 64);
            #pragma unroll
            for (int q = 0; q < 16; ++q)
                wr[q] = ld_b64_sc(wbase + q * 512);
            waitcnt_vm0();
            unsigned bad = 0;
            #pragma unroll
            for (int kc = 0; kc < 32; ++kc) {
                bad |= (yreg[kc][0] ^ sgnr) & 0x80008000u;
                bad |= (yreg[kc][1] ^ sgnr) & 0x80008000u;
                bad |= (yreg[kc][2] ^ sgnr) & 0x80008000u;
                bad |= (yreg[kc][3] ^ sgnr) & 0x80008000u;
            }
            #pragma unroll
            for (int q = 0; q < 16; ++q)
                bad |= (wr[q][1] ^ want);
            okc = __all(bad == 0);
        } while (!okc);

        // per-b global max: each lane maxes its 16 q's, then combine w-halves
        float gm = __builtin_bit_cast(float, wr[0][0]);
        #pragma unroll
        for (int q = 1; q < 16; ++q)
            gm = fmaxf(gm, __builtin_bit_cast(float, wr[q][0]));
        gm = fmaxf(gm, __shfl_xor(gm, 32));

        float Gcur[4];
        #pragma unroll
        for (int r = 0; r < 4; ++r) Gcur[r] = __shfl(gm, mb * 16 + g * 4 + r);

        // ---- S[b, i-slice] = sum_j expA[i,j] * Y[b,j]  (Y possibly negated) ----
        f32x4 acc0 = {0.f, 0.f, 0.f, 0.f}, acc1 = {0.f, 0.f, 0.f, 0.f};
        {
            const int ia = np * 32 + li;
            const int ib = ia + 16;
            const int basea = ia * 2048 + g * 16, xa = (ia & 7) << 4;
            const int baseb = ib * 2048 + g * 16, xb = (ib & 7) << 4;
            #pragma unroll
            for (int kc = 0; kc < 32; ++kc) {
                bf16x8 af0 = *(const bf16x8*)(Asl + ((basea + kc * 64) ^ xa));
                bf16x8 af1 = *(const bf16x8*)(Asl + ((baseb + kc * 64) ^ xb));
                bf16x8 yf  = __builtin_bit_cast(bf16x8, yreg[kc]);
                acc0 = __builtin_amdgcn_mfma_f32_16x16x32_bf16(yf, af0, acc0, 0, 0, 0);
                acc1 = __builtin_amdgcn_mfma_f32_16x16x32_bf16(yf, af1, acc1, 0, 0, 0);
            }
        }

        float yv[2][4];
        #pragma unroll
        for (int r = 0; r < 4; ++r) {
            yv[0][r] = Nprev[r] + __logf(acc0[r] * negr) + ereg[0][r];
            yv[1][r] = Nprev[r] + __logf(acc1[r] * negr) + ereg[1][r];
        }

        if (s < Tdim - 1) {
            publish_wave(yv, Gcur,
                         Yb + (size_t)par_w * (NWG * 4096) + p * 4096,
                         wrec + (size_t)par_w * 8192 + (size_t)p * 512 + w * 128,
                         li, g, np, b0, (unsigned)(s + 1), negw);
            #pragma unroll
            for (int r = 0; r < 4; ++r) Nprev[r] = Gcur[r];
            #pragma unroll
            for (int u = 0; u < 2; ++u)
                #pragma unroll
                for (int r = 0; r < 4; ++r) ereg[u][r] = eregN[u][r];
        } else {
            #pragma unroll
            for (int r = 0; r < 4; ++r) {
                float pa = __expf(gl[0] + yv[0][r] - Gcur[r])
                         + __expf(gl[1] + yv[1][r] - Gcur[r]);
                pa += __shfl_xor(pa, 1, 16);
                pa += __shfl_xor(pa, 2, 16);
                pa += __shfl_xor(pa, 4, 16);
                pa += __shfl_xor(pa, 8, 16);
                if (li == 0) {
                    atomicAdd(&Psum[b0 + r], pa);
                    if (p == 0) Rbuf[b0 + r] = Gcur[r];
                }
            }
        }
    }
}

__global__ void k_final(const float* __restrict__ Psum, const float* __restrict__ Rbuf,
                        float* __restrict__ out) {
    int b = threadIdx.x;
    if (b < 32) out[b] = Rbuf[b] + __logf(Psum[b]);
}

extern "C" void kernel_launch(void* const* d_in, const int* in_sizes, int n_in,
                              void* d_out, int out_size, void* d_ws, size_t ws_size,
                              hipStream_t stream) {
    const int*   x     = (const int*)d_in[0];
    const float* alpha = (const float*)d_in[1];
    const float* beta  = (const float*)d_in[2];
    const float* gamma = (const float*)d_in[3];

    char* ws = (char*)d_ws;
    __bf16* Abf  = (__bf16*)(ws + OFF_ABF);
    char*   Yb   = ws + OFF_YBUF;
    float*  Psum = (float*)(ws + OFF_PSUM);
    float*  Rbuf = (float*)(ws + OFF_RBUF);
    char*   wrec = ws + OFF_WREC;
    float*  Ebuf = (float*)(ws + OFF_E);

    int useE = (ws_size >= WS_E_NEED) ? 1 : 0;

    // every launch: Ybuf -> 0xAA (bf16 sign=1 => stale), Psum/Rbuf/wrec -> 0
    (void)hipMemsetAsync(ws + OFF_YBUF, 0xAA, 131072, stream);
    (void)hipMemsetAsync(ws + OFF_PSUM, 0, OFF_END0 - OFF_PSUM, stream);

    hipLaunchKernelGGL(k_expA, dim3((Hdim * Hdim) / (256 * 4)), dim3(256), 0, stream, alpha, Abf);

    if (useE)
        hipLaunchKernelGGL(k_gather, dim3(Tdim * Bdim), dim3(256), 0, stream, x, beta, Ebuf);

    (void)hipFuncSetAttribute((const void*)k_hmm, hipFuncAttributeMaxDynamicSharedMemorySize, SMEM_BYTES);
    hipLaunchKernelGGL(k_hmm, dim3(NWG), dim3(256), SMEM_BYTES, stream,
                       x, beta, gamma, Abf, Yb, wrec, Psum, Rbuf,
                       useE ? Ebuf : (const float*)nullptr, useE);

    hipLaunchKernelGGL(k_final, dim3(1), dim3(64), 0, stream, Psum, Rbuf, (float*)d_out);
}

// Round 9
// 2051.565 us; speedup vs baseline: 1.4231x; 1.4231x over previous
//
#include <hip/hip_runtime.h>
#include <hip/hip_bf16.h>

// HMM backward recursion, B=32, T=256, H=1024, V=50257.
// y_s[b,i] = N_{s-1}[b] + log( sum_j expA[i,j] * Y_{s-1}[b,j] ) + e_t[b,i]
// Y_s = exp(y_s - N_s), N_s = max_i y_{s-1}[b,i] (one-step-stale upper bound).
// 16 persistent WGs. Barrier-free step loop (round-7 structure).
// PUBLISH side uses device-scope atomics (execute at MALL/L3 coherence point,
// cross-XCD coherent per m20) instead of sc0sc1 write-through stores, so the
// pre-flag vmcnt drain waits for an L3 ack, not an HBM ack.
// CONSUME side: sc0sc1 bypass loads (L3-served), per-wave flag poll.

#define Hdim 1024
#define Bdim 32
#define Tdim 256
#define Vdim 50257
#define NWG  16
#define SLICE 64

typedef __attribute__((ext_vector_type(8))) __bf16 bf16x8;
typedef __attribute__((ext_vector_type(4))) float  f32x4;
typedef __attribute__((ext_vector_type(4))) unsigned u32x4;
typedef __attribute__((ext_vector_type(2))) unsigned u32x2;

// workspace layout (bytes)
#define OFF_ABF   0                          // exp(alpha) bf16: 2 MB
#define OFF_YBUF  2097152                    // [2][16][4096B] = 131072
#define OFF_PSUM  (OFF_YBUF + 131072)        // 32 f32 (pad 128)
#define OFF_RBUF  (OFF_PSUM + 128)           // 32 f32 (pad 128)
#define OFF_WREC  (OFF_RBUF + 128)           // [2][16][4] x 64B = 8192
#define OFF_FLG   (OFF_WREC + 8192)          // [2][64] x 64B = 8192
#define OFF_END0  (OFF_FLG + 8192)
#define OFF_E     (((OFF_END0) + 4095) & ~4095)
#define WS_E_NEED ((size_t)OFF_E + (size_t)Tdim * Bdim * Hdim * 4)

// LDS carve
#define SM_A       131072                    // 64 rows x 1024 bf16 (swizzled)
#define SMEM_BYTES (SM_A + 256)

// ---- device-scope atomic publish helpers (execute at L3/MALL, no return) ----
__device__ __forceinline__ void at_swap_b32(void* p, unsigned v) {
    asm volatile("global_atomic_swap %0, %1, off" :: "v"(p), "v"(v) : "memory");
}
__device__ __forceinline__ void at_swap_b64(void* p, u32x2 v) {
    asm volatile("global_atomic_swap_x2 %0, %1, off" :: "v"(p), "v"(v) : "memory");
}
// ---- sc0 sc1 (bypass, L3-served) consume helpers ----
__device__ __forceinline__ u32x4 ld_b128_sc(const void* p) {
    u32x4 r;
    asm volatile("global_load_dwordx4 %0, %1, off sc0 sc1" : "=v"(r) : "v"(p) : "memory");
    return r;
}
__device__ __forceinline__ float ld_f32_sc(const void* p) {
    float r;
    asm volatile("global_load_dword %0, %1, off sc0 sc1" : "=v"(r) : "v"(p) : "memory");
    return r;
}
__device__ __forceinline__ unsigned ld_u32sync_sc(const void* p) {
    unsigned r;
    asm volatile("global_load_dword %0, %1, off sc0 sc1\n\ts_waitcnt vmcnt(0)"
                 : "=v"(r) : "v"(p) : "memory");
    return r;
}
__device__ __forceinline__ void waitcnt_vm0() {
    asm volatile("s_waitcnt vmcnt(0)" ::: "memory");
    __builtin_amdgcn_sched_barrier(0);
}
__device__ __forceinline__ void waitcnt_vm32() {
    asm volatile("s_waitcnt vmcnt(32)" ::: "memory");
    __builtin_amdgcn_sched_barrier(0);
}

__global__ void k_expA(const float* __restrict__ alpha, __bf16* __restrict__ Abf) {
    int idx = (blockIdx.x * 256 + threadIdx.x) * 4;
    float4 v = *(const float4*)(alpha + idx);
    union { __bf16 h[4]; uint2 u; } cv;
    cv.h[0] = (__bf16)__expf(v.x);
    cv.h[1] = (__bf16)__expf(v.y);
    cv.h[2] = (__bf16)__expf(v.z);
    cv.h[3] = (__bf16)__expf(v.w);
    *(uint2*)(Abf + idx) = cv.u;
}

// E[t][b][i] = beta[i, x[b,t]]
__global__ void k_gather(const int* __restrict__ x, const float* __restrict__ beta,
                         float* __restrict__ E) {
    int tb = blockIdx.x;            // t*32 + b
    int t  = tb >> 5, b = tb & 31;
    int xv = x[b * Tdim + t];
    int i  = threadIdx.x * 4;
    float4 v;
    v.x = beta[(size_t)(i + 0) * Vdim + xv];
    v.y = beta[(size_t)(i + 1) * Vdim + xv];
    v.z = beta[(size_t)(i + 2) * Vdim + xv];
    v.w = beta[(size_t)(i + 3) * Vdim + xv];
    *(float4*)(E + ((size_t)t * Bdim + b) * Hdim + i) = v;
}

__device__ __forceinline__ void load_e(const float* __restrict__ E,
                                       const float* __restrict__ beta,
                                       const int* __restrict__ x,
                                       int t, int b0, int i0, int useE, float e[2][4]) {
    if (useE) {
        #pragma unroll
        for (int u = 0; u < 2; ++u)
            #pragma unroll
            for (int r = 0; r < 4; ++r)
                e[u][r] = E[((size_t)t * Bdim + (b0 + r)) * Hdim + i0 + u * 16];
    } else {
        int xv[4];
        #pragma unroll
        for (int r = 0; r < 4; ++r) xv[r] = x[(b0 + r) * Tdim + t];
        #pragma unroll
        for (int u = 0; u < 2; ++u)
            #pragma unroll
            for (int r = 0; r < 4; ++r)
                e[u][r] = beta[(size_t)(i0 + u * 16) * Vdim + xv[r]];
    }
}

// Per-WAVE publish via device-scope atomics: Y as paired-lane dword swaps,
// per-b maxes as swap_x2, own vmcnt drain (L3 ack), own flag swap.
__device__ __forceinline__ void publish_wave(const float y[2][4], const float Gc[4],
                                             char* Yblk,     // Ybuf[par] + p*4096
                                             char* wrec_pw,  // wrec[par][p][w]
                                             char* flg_pw,   // flg[par][p*4+w]
                                             int l, int li, int g, int np, int b0,
                                             unsigned seq) {
    float mx[4];
    unsigned pk[2][4];
    #pragma unroll
    for (int r = 0; r < 4; ++r) {
        #pragma unroll
        for (int u = 0; u < 2; ++u) {
            float Yn = __expf(y[u][r] - Gc[r]);
            __bf16 h = (__bf16)Yn;
            unsigned hv = (unsigned)__builtin_bit_cast(unsigned short, h);
            unsigned ov = (unsigned)__shfl_xor((int)hv, 1);
            pk[u][r] = hv | (ov << 16);          // even lane: (self, l+1)
        }
        float m = fmaxf(y[0][r], y[1][r]);
        m = fmaxf(m, __shfl_xor(m, 1, 16));
        m = fmaxf(m, __shfl_xor(m, 2, 16));
        m = fmaxf(m, __shfl_xor(m, 4, 16));
        m = fmaxf(m, __shfl_xor(m, 8, 16));
        mx[r] = m;
    }
    if (!(l & 1)) {
        #pragma unroll
        for (int r = 0; r < 4; ++r)
            #pragma unroll
            for (int u = 0; u < 2; ++u)
                at_swap_b32(Yblk + (b0 + r) * 128 + (np * 32 + u * 16 + li) * 2,
                            pk[u][r]);
    }
    if (li == 0) {
        u32x2 p0 = { __builtin_bit_cast(unsigned, mx[0]),
                     __builtin_bit_cast(unsigned, mx[1]) };
        u32x2 p1 = { __builtin_bit_cast(unsigned, mx[2]),
                     __builtin_bit_cast(unsigned, mx[3]) };
        at_swap_b64(wrec_pw + g * 16 + 0, p0);
        at_swap_b64(wrec_pw + g * 16 + 8, p1);
    }
    asm volatile("s_waitcnt vmcnt(0)" ::: "memory");   // L3 ack for atomics
    if ((threadIdx.x & 63) == 0) at_swap_b32(flg_pw, seq);
}

__launch_bounds__(256, 1)
__global__ void k_hmm(const int* __restrict__ x,
                      const float* __restrict__ beta,
                      const float* __restrict__ gamma,
                      const __bf16* __restrict__ Abf,
                      char* __restrict__ Yb,        // [2][16][4096B]
                      char* __restrict__ wrec,      // [2][16][4] x 64B
                      char* __restrict__ flg,       // [2][64] x 64B
                      float* __restrict__ Psum,
                      float* __restrict__ Rbuf,
                      const float* __restrict__ Ebuf,
                      int useE)
{
    extern __shared__ char smem[];
    char* Asl = smem;

    const int p   = blockIdx.x;
    const int tid = threadIdx.x;
    const int w   = tid >> 6;
    const int l   = tid & 63;
    const int g   = l >> 4;
    const int li  = l & 15;
    const int mb  = w & 1;
    const int np  = w >> 1;
    const int b0  = mb * 16 + g * 4;
    const int i0  = p * SLICE + np * 32 + li;

    // ---- stage A slice into LDS, XOR-swizzled for b128 reads ----
    #pragma unroll
    for (int rep = 0; rep < 32; ++rep) {
        int flat = rep * 256 + tid;
        int row  = flat >> 7;
        int c16  = flat & 127;
        uint4 v = *(const uint4*)((const char*)Abf + (size_t)(p * 64 + row) * 2048 + c16 * 16);
        int off = (row * 2048 + c16 * 16) ^ ((row & 7) << 4);
        *(uint4*)(Asl + off) = v;
    }
    __syncthreads();    // only barrier in the kernel (A staging)

    // ---- init: y0 = e[:, T-1], publish per-wave ----
    {
        float y0[2][4];
        load_e(Ebuf, beta, x, Tdim - 1, b0, i0, useE, y0);
        float Gc0[4] = {0.f, 0.f, 0.f, 0.f};
        publish_wave(y0, Gc0, Yb + p * 4096,
                     wrec + (size_t)p * 256 + w * 64,
                     flg + (size_t)(p * 4 + w) * 64,
                     l, li, g, np, b0, 1u);
    }

    float Nprev[4] = {0.f, 0.f, 0.f, 0.f};
    float ereg[2][4];
    load_e(Ebuf, beta, x, Tdim - 2, b0, i0, useE, ereg);

    for (int s = 1; s < Tdim; ++s) {
        const int t     = Tdim - 1 - s;
        const int par_r = (s - 1) & 1;
        const int par_w = s & 1;

        // prefetch next step's e; drain BEFORE polling so the detect loop
        // never waits on an E (possibly HBM) load
        float eregN[2][4];
        if (s < Tdim - 1) load_e(Ebuf, beta, x, t - 1, b0, i0, useE, eregN);
        float gl[2] = {0.f, 0.f};
        if (s == Tdim - 1) { gl[0] = gamma[i0]; gl[1] = gamma[i0 + 16]; }
        waitcnt_vm0();

        // ---- poll all 64 producer-wave flags (each wave independently) ----
        {
            const char* fp = flg + (size_t)par_r * 4096 + l * 64;
            while (!__all((int)(ld_u32sync_sc(fp) >= (unsigned)s))) {}
        }

        // ---- issue Y loads (32 b128), then wrec loads (32 f32, lanes<32) ----
        const char* Ybase = Yb + (size_t)par_r * (NWG * 4096);
        const char* yrow  = Ybase + (mb * 16 + li) * 128 + g * 16;
        u32x4 yreg[32];
        #pragma unroll
        for (int kc = 0; kc < 32; ++kc)
            yreg[kc] = ld_b128_sc(yrow + (kc >> 1) * 4096 + (kc & 1) * 64);

        float gmv[32];
        {
            const char* wbase = wrec + (size_t)par_r * 4096;
            if (l < 32) {
                int bmb = l >> 4;          // 16-block of b
                int idx = (l & 15) * 4;
                #pragma unroll
                for (int q = 0; q < 16; ++q) {
                    gmv[2 * q]     = ld_f32_sc(wbase + q * 256 + bmb * 64 + idx);
                    gmv[2 * q + 1] = ld_f32_sc(wbase + q * 256 + (bmb + 2) * 64 + idx);
                }
            }
        }

        waitcnt_vm32();   // Y loads (oldest 32) done; wrec still in flight

        // ---- S[b, i-slice] = sum_j expA[i,j] * Y[b,j] ----
        f32x4 acc0 = {0.f, 0.f, 0.f, 0.f}, acc1 = {0.f, 0.f, 0.f, 0.f};
        {
            const int ia = np * 32 + li;
            const int ib = ia + 16;
            const int basea = ia * 2048 + g * 16, xa = (ia & 7) << 4;
            const int baseb = ib * 2048 + g * 16, xb = (ib & 7) << 4;
            #pragma unroll
            for (int kc = 0; kc < 32; ++kc) {
                bf16x8 af0 = *(const bf16x8*)(Asl + ((basea + kc * 64) ^ xa));
                bf16x8 af1 = *(const bf16x8*)(Asl + ((baseb + kc * 64) ^ xb));
                bf16x8 yf  = __builtin_bit_cast(bf16x8, yreg[kc]);
                acc0 = __builtin_amdgcn_mfma_f32_16x16x32_bf16(yf, af0, acc0, 0, 0, 0);
                acc1 = __builtin_amdgcn_mfma_f32_16x16x32_bf16(yf, af1, acc1, 0, 0, 0);
            }
        }

        waitcnt_vm0();    // wrec loads done

        // per-b global max in registers + wave-local broadcast (no LDS)
        float gm = -3.0e38f;
        if (l < 32) {
            #pragma unroll
            for (int q = 0; q < 32; ++q) gm = fmaxf(gm, gmv[q]);
        }
        float Gcur[4];
        #pragma unroll
        for (int r = 0; r < 4; ++r) Gcur[r] = __shfl(gm, b0 + r);

        float yv[2][4];
        #pragma unroll
        for (int r = 0; r < 4; ++r) {
            yv[0][r] = Nprev[r] + __logf(acc0[r]) + ereg[0][r];
            yv[1][r] = Nprev[r] + __logf(acc1[r]) + ereg[1][r];
        }

        if (s < Tdim - 1) {
            publish_wave(yv, Gcur,
                         Yb + (size_t)par_w * (NWG * 4096) + p * 4096,
                         wrec + (size_t)par_w * 4096 + (size_t)p * 256 + w * 64,
                         flg + (size_t)par_w * 4096 + (size_t)(p * 4 + w) * 64,
                         l, li, g, np, b0, (unsigned)(s + 1));
            #pragma unroll
            for (int r = 0; r < 4; ++r) Nprev[r] = Gcur[r];
            #pragma unroll
            for (int u = 0; u < 2; ++u)
                #pragma unroll
                for (int r = 0; r < 4; ++r) ereg[u][r] = eregN[u][r];
        } else {
            #pragma unroll
            for (int r = 0; r < 4; ++r) {
                float pa = __expf(gl[0] + yv[0][r] - Gcur[r])
                         + __expf(gl[1] + yv[1][r] - Gcur[r]);
                pa += __shfl_xor(pa, 1, 16);
                pa += __shfl_xor(pa, 2, 16);
                pa += __shfl_xor(pa, 4, 16);
                pa += __shfl_xor(pa, 8, 16);
                if (li == 0) {
                    atomicAdd(&Psum[b0 + r], pa);
                    if (p == 0) Rbuf[b0 + r] = Gcur[r];
                }
            }
        }
    }
}

__global__ void k_final(const float* __restrict__ Psum, const float* __restrict__ Rbuf,
                        float* __restrict__ out) {
    int b = threadIdx.x;
    if (b < 32) out[b] = Rbuf[b] + __logf(Psum[b]);
}

extern "C" void kernel_launch(void* const* d_in, const int* in_sizes, int n_in,
                              void* d_out, int out_size, void* d_ws, size_t ws_size,
                              hipStream_t stream) {
    const int*   x     = (const int*)d_in[0];
    const float* alpha = (const float*)d_in[1];
    const float* beta  = (const float*)d_in[2];
    const float* gamma = (const float*)d_in[3];

    char* ws = (char*)d_ws;
    __bf16* Abf  = (__bf16*)(ws + OFF_ABF);
    char*   Yb   = ws + OFF_YBUF;
    float*  Psum = (float*)(ws + OFF_PSUM);
    float*  Rbuf = (float*)(ws + OFF_RBUF);
    char*   wrec = ws + OFF_WREC;
    char*   flg  = ws + OFF_FLG;
    float*  Ebuf = (float*)(ws + OFF_E);

    int useE = (ws_size >= WS_E_NEED) ? 1 : 0;

    // zero Psum/Rbuf/wrec/flags every launch
    (void)hipMemsetAsync(ws + OFF_PSUM, 0, OFF_END0 - OFF_PSUM, stream);

    hipLaunchKernelGGL(k_expA, dim3((Hdim * Hdim) / (256 * 4)), dim3(256), 0, stream, alpha, Abf);

    if (useE)
        hipLaunchKernelGGL(k_gather, dim3(Tdim * Bdim), dim3(256), 0, stream, x, beta, Ebuf);

    (void)hipFuncSetAttribute((const void*)k_hmm, hipFuncAttributeMaxDynamicSharedMemorySize, SMEM_BYTES);
    hipLaunchKernelGGL(k_hmm, dim3(NWG), dim3(256), SMEM_BYTES, stream,
                       x, beta, gamma, Abf, Yb, wrec, flg, Psum, Rbuf,
                       useE ? Ebuf : (const float*)nullptr, useE);

    hipLaunchKernelGGL(k_final, dim3(1), dim3(64), 0, stream, Psum, Rbuf, (float*)d_out);
}